// Round 1
// baseline (1156.034 us; speedup 1.0000x reference)
//
#include <hip/hip_runtime.h>
#include <math.h>

// Problem constants
#define B_  256
#define T_  32
#define S_  128
#define I_  256
#define H_  1024
#define O_  256
#define G4  4096   // 4*H
#define K2  2048   // 2*H

typedef __attribute__((ext_vector_type(8))) short bf16x8;
typedef __attribute__((ext_vector_type(4))) float f32x4;

#define MFMA16(a, b, c) __builtin_amdgcn_mfma_f32_16x16x32_bf16(a, b, c, 0, 0, 0)

__device__ __forceinline__ unsigned short f2bf(float f) {
    unsigned int u = __float_as_uint(f);
    u = (u + 0x7FFFu + ((u >> 16) & 1u)) >> 16;
    return (unsigned short)u;
}
__device__ __forceinline__ unsigned int pack2(float a, float b) {
    return (unsigned int)f2bf(a) | ((unsigned int)f2bf(b) << 16);
}
__device__ __forceinline__ float sigm(float x) { return 1.0f / (1.0f + __expf(-x)); }

// ---------------------------------------------------------------------------
// prep: convert/reorder weights to bf16, convert x (zero t=0), zero h0/h1/c.
// Gate reorder: orig row r in [0,4H): gate=r/H, u=r%H -> n = 4u+gate, so a
// 128-wide N tile holds 32 complete units (all 4 gates) for the fused cell.
// ---------------------------------------------------------------------------
__global__ void prep_kernel(
    const float* __restrict__ x, const float* __restrict__ Wih,
    const float* __restrict__ Whh, const float* __restrict__ bih,
    const float* __restrict__ bhh, const float* __restrict__ Wfc,
    unsigned short* __restrict__ WihR, unsigned short* __restrict__ WhhR,
    unsigned short* __restrict__ WfcR, float* __restrict__ biasR,
    unsigned short* __restrict__ xs, unsigned short* __restrict__ h0,
    unsigned short* __restrict__ h1, float* __restrict__ c)
{
    const long NWHH = (long)G4 * H_;      // 4,194,304
    const long NWIH = (long)G4 * I_;      // 1,048,576
    const long NWFC = (long)O_ * K2;      //   524,288
    const long NB   = G4;
    const long NX   = (long)B_ * T_ * I_; // 2,097,152
    const long NH   = (long)B_ * H_;      //   262,144
    const long total = NWHH + NWIH + NWFC + NB + NX + 3 * NH;
    for (long i = (long)blockIdx.x * blockDim.x + threadIdx.x; i < total;
         i += (long)gridDim.x * blockDim.x) {
        long j = i;
        if (j < NWHH) {
            int r = (int)(j >> 10), k = (int)(j & 1023);
            int n = ((r & 1023) << 2) | (r >> 10);
            WhhR[(long)n * H_ + k] = f2bf(Whh[j]);
            continue;
        }
        j -= NWHH;
        if (j < NWIH) {
            int r = (int)(j >> 8), k = (int)(j & 255);
            int n = ((r & 1023) << 2) | (r >> 10);
            WihR[(long)n * I_ + k] = f2bf(Wih[j]);
            continue;
        }
        j -= NWIH;
        if (j < NWFC) { WfcR[j] = f2bf(Wfc[j]); continue; }
        j -= NWFC;
        if (j < NB) {
            int r = (int)j;
            int n = ((r & 1023) << 2) | (r >> 10);
            biasR[n] = bih[r] + bhh[r];
            continue;
        }
        j -= NB;
        if (j < NX) {
            int t = (int)((j >> 8) & 31);
            xs[j] = (t == 0) ? (unsigned short)0 : f2bf(x[j]);
            continue;
        }
        j -= NX;
        if (j < NH) { h0[j] = 0; continue; }
        j -= NH;
        if (j < NH) { h1[j] = 0; continue; }
        j -= NH;
        c[j] = 0.0f;
    }
}

// ---------------------------------------------------------------------------
// step: gates = [x_t, h_prev] @ [WihR; WhhR]^T + biasR, fused LSTM cell.
// M=256 (batch), N=4096 (4u+gate interleaved), K=1280. Tile 64x128, BK=32,
// 4 waves each 32x64 (2x4 of 16x16x32 MFMA). Epilogue: gates -> LDS ->
// sigmoid/tanh -> c,h update. grid(32,4).
// ---------------------------------------------------------------------------
__global__ __launch_bounds__(256) void step_kernel(
    const unsigned short* __restrict__ xs,   // [B][T][I] bf16
    const unsigned short* __restrict__ WihR, // [4H][I]
    const unsigned short* __restrict__ WhhR, // [4H][H]
    const float* __restrict__ biasR,         // [4H]
    const unsigned short* __restrict__ hprev,// [B][H] bf16
    unsigned short* __restrict__ hnext,      // [B][H] bf16
    float* __restrict__ c,                   // [B][H]
    unsigned short* __restrict__ hall,       // [B][T][H] bf16
    int t)
{
    __shared__ __align__(16) char smem[64 * 132 * 4];  // 33792 B
    unsigned short* As = (unsigned short*)smem;              // [64][40] (pad 8)
    unsigned short* Bs = (unsigned short*)(smem + 64 * 40 * 2); // [128][40]
    float* Gs = (float*)smem;                                // [64][132] epilogue

    const int tid = threadIdx.x;
    const int lane = tid & 63, wave = tid >> 6;
    const int wm = wave >> 1, wn = wave & 1;
    const int quad = lane >> 4, l16 = lane & 15;
    const int n0 = blockIdx.x * 128, m0 = blockIdx.y * 64;

    const int arow = tid >> 2, akc = (tid & 3) * 8;
    const int brow = tid >> 1, bkc = (tid & 1) * 16;

    f32x4 acc[2][4];
    const f32x4 z = {0.f, 0.f, 0.f, 0.f};
#pragma unroll
    for (int i = 0; i < 2; i++)
#pragma unroll
        for (int j = 0; j < 4; j++) acc[i][j] = z;

    for (int k0 = 0; k0 < I_ + H_; k0 += 32) {
        {
            int kg = k0 + akc;
            const unsigned short* src = (kg < I_)
                ? xs + ((long)(m0 + arow) * T_ + t) * I_ + kg
                : hprev + (long)(m0 + arow) * H_ + (kg - I_);
            *(uint4*)(As + arow * 40 + akc) = *(const uint4*)src;
        }
        {
            int kg = k0 + bkc;
            const unsigned short* src = (kg < I_)
                ? WihR + (long)(n0 + brow) * I_ + kg
                : WhhR + (long)(n0 + brow) * H_ + (kg - I_);
            *(uint4*)(Bs + brow * 40 + bkc)     = *(const uint4*)src;
            *(uint4*)(Bs + brow * 40 + bkc + 8) = *(const uint4*)(src + 8);
        }
        __syncthreads();
        bf16x8 a0 = *(const bf16x8*)(As + (wm * 32 + l16) * 40 + quad * 8);
        bf16x8 a1 = *(const bf16x8*)(As + (wm * 32 + 16 + l16) * 40 + quad * 8);
#pragma unroll
        for (int j = 0; j < 4; j++) {
            bf16x8 bb = *(const bf16x8*)(Bs + (wn * 64 + j * 16 + l16) * 40 + quad * 8);
            acc[0][j] = MFMA16(a0, bb, acc[0][j]);
            acc[1][j] = MFMA16(a1, bb, acc[1][j]);
        }
        __syncthreads();
    }
    // gates -> LDS (C layout: row = quad*4+reg, col = lane&15)
#pragma unroll
    for (int i = 0; i < 2; i++)
#pragma unroll
        for (int j = 0; j < 4; j++)
#pragma unroll
            for (int r = 0; r < 4; r++) {
                int row = wm * 32 + i * 16 + quad * 4 + r;
                int col = wn * 64 + j * 16 + l16;
                Gs[row * 132 + col] = acc[i][j][r] + biasR[n0 + col];
            }
    __syncthreads();
    // fused cell: 64 rows x 32 units per block
    for (int p = tid; p < 2048; p += 256) {
        int row = p >> 5, u = p & 31;
        float gi = Gs[row * 132 + u * 4 + 0];
        float gf = Gs[row * 132 + u * 4 + 1];
        float gg = Gs[row * 132 + u * 4 + 2];
        float go = Gs[row * 132 + u * 4 + 3];
        int b = m0 + row;
        int jg = (n0 >> 2) + u;
        float ii = sigm(gi), ff = sigm(gf), g3 = tanhf(gg), oo = sigm(go);
        float cn = ff * c[(long)b * H_ + jg] + ii * g3;
        float hh = oo * tanhf(cn);
        c[(long)b * H_ + jg] = cn;
        unsigned short hb = f2bf(hh);
        hnext[(long)b * H_ + jg] = hb;
        hall[((long)b * T_ + t) * H_ + jg] = hb;
    }
}

// ---------------------------------------------------------------------------
// attn: one block per b. scores = H_t(32x1024) @ enc[b]^T (MFMA bf16, enc
// converted during staging), fp32 softmax (probs -> d_out), ctx via fp32
// vector FMA from global enc (precision + no transpose), writes cat rows
// [ctx_bf16 | h_bf16] for the FC GEMM.
// ---------------------------------------------------------------------------
__global__ __launch_bounds__(256) void attn_kernel(
    const float* __restrict__ enc,           // [B][S][H] fp32
    const unsigned short* __restrict__ hall, // [B][T][H] bf16
    float* __restrict__ probs,               // [B][T][S]
    unsigned short* __restrict__ cat)        // [B*T][2H] bf16
{
    __shared__ __align__(16) unsigned short As2[32 * 72];   // h tile, pad 8
    __shared__ __align__(16) unsigned short Bs2[128 * 72];  // enc tile, pad 8
    __shared__ __align__(16) float Sc[32 * 132];            // scores then probs

    const int tid = threadIdx.x;
    const int lane = tid & 63, wave = tid >> 6;
    const int mw = wave & 1, nw = wave >> 1;
    const int quad = lane >> 4, l16 = lane & 15;
    const int b = blockIdx.x;

    f32x4 acc[4];
    const f32x4 z = {0.f, 0.f, 0.f, 0.f};
#pragma unroll
    for (int j = 0; j < 4; j++) acc[j] = z;

    const int arow = tid >> 3, akc = (tid & 7) * 8;   // [32][64]
    const int brow = tid >> 1, bkc = (tid & 1) * 32;  // [128][64]

    for (int k0 = 0; k0 < H_; k0 += 64) {
        *(uint4*)(As2 + arow * 72 + akc) =
            *(const uint4*)(hall + ((long)b * T_ + arow) * H_ + k0 + akc);
        {
            const float* ep = enc + ((long)b * S_ + brow) * H_ + k0 + bkc;
#pragma unroll
            for (int i = 0; i < 4; i++) {
                float4 f0 = *(const float4*)(ep + i * 8);
                float4 f1 = *(const float4*)(ep + i * 8 + 4);
                uint4 v;
                v.x = pack2(f0.x, f0.y);
                v.y = pack2(f0.z, f0.w);
                v.z = pack2(f1.x, f1.y);
                v.w = pack2(f1.z, f1.w);
                *(uint4*)(Bs2 + brow * 72 + bkc + i * 8) = v;
            }
        }
        __syncthreads();
#pragma unroll
        for (int ks = 0; ks < 2; ks++) {
            bf16x8 a = *(const bf16x8*)(As2 + (mw * 16 + l16) * 72 + ks * 32 + quad * 8);
#pragma unroll
            for (int j = 0; j < 4; j++) {
                bf16x8 bb = *(const bf16x8*)(Bs2 + (nw * 64 + j * 16 + l16) * 72 + ks * 32 + quad * 8);
                acc[j] = MFMA16(a, bb, acc[j]);
            }
        }
        __syncthreads();
    }
#pragma unroll
    for (int j = 0; j < 4; j++)
#pragma unroll
        for (int r = 0; r < 4; r++)
            Sc[(mw * 16 + quad * 4 + r) * 132 + nw * 64 + j * 16 + l16] = acc[j][r];
    __syncthreads();
    // softmax: wave handles 8 rows; 128 cols = 2 per lane
    for (int r = 0; r < 8; r++) {
        int row = wave * 8 + r;
        float v0 = Sc[row * 132 + lane];
        float v1 = Sc[row * 132 + 64 + lane];
        float mx = fmaxf(v0, v1);
#pragma unroll
        for (int off = 32; off > 0; off >>= 1) mx = fmaxf(mx, __shfl_xor(mx, off));
        float e0 = __expf(v0 - mx), e1 = __expf(v1 - mx);
        float s = e0 + e1;
#pragma unroll
        for (int off = 32; off > 0; off >>= 1) s += __shfl_xor(s, off);
        float inv = 1.0f / s;
        float p0 = e0 * inv, p1 = e1 * inv;
        probs[((long)b * T_ + row) * S_ + lane] = p0;
        probs[((long)b * T_ + row) * S_ + 64 + lane] = p1;
        Sc[row * 132 + lane] = p0;
        Sc[row * 132 + 64 + lane] = p1;
    }
    __syncthreads();
    // ctx: thread owns 4 h-cols, t in registers, stream enc rows once (fp32)
    float ax[32], ay[32], az[32], aw[32];
#pragma unroll
    for (int t2 = 0; t2 < 32; t2++) { ax[t2] = 0; ay[t2] = 0; az[t2] = 0; aw[t2] = 0; }
    const float* ep0 = enc + (long)b * S_ * H_ + tid * 4;
    for (int s = 0; s < S_; s++) {
        float4 e = *(const float4*)(ep0 + (long)s * H_);
#pragma unroll
        for (int t2 = 0; t2 < 32; t2++) {
            float p = Sc[t2 * 132 + s];  // broadcast
            ax[t2] += p * e.x; ay[t2] += p * e.y;
            az[t2] += p * e.z; aw[t2] += p * e.w;
        }
    }
#pragma unroll
    for (int t2 = 0; t2 < 32; t2++) {
        uint2 v;
        v.x = pack2(ax[t2], ay[t2]);
        v.y = pack2(az[t2], aw[t2]);
        *(uint2*)(cat + ((long)(b * T_ + t2)) * K2 + tid * 4) = v;
    }
    // copy h into second half of cat rows
    const uint4* hs = (const uint4*)(hall + (long)b * T_ * H_);
    for (int i = tid; i < (T_ * H_) / 8; i += 256) {
        int t2 = i >> 7, cpos = i & 127;
        *(uint4*)(cat + ((long)(b * T_ + t2)) * K2 + H_ + cpos * 8) = hs[i];
    }
}

// ---------------------------------------------------------------------------
// fc: out = cat(8192x2048) @ WfcR^T (256x2048) + bfc. Tile 64x128, grid(2,128).
// ---------------------------------------------------------------------------
__global__ __launch_bounds__(256) void fc_kernel(
    const unsigned short* __restrict__ cat,
    const unsigned short* __restrict__ WfcR,
    const float* __restrict__ bfc,
    float* __restrict__ out)
{
    __shared__ __align__(16) unsigned short As[64 * 40];
    __shared__ __align__(16) unsigned short Bs[128 * 40];

    const int tid = threadIdx.x;
    const int lane = tid & 63, wave = tid >> 6;
    const int wm = wave >> 1, wn = wave & 1;
    const int quad = lane >> 4, l16 = lane & 15;
    const int n0 = blockIdx.x * 128, m0 = blockIdx.y * 64;

    const int arow = tid >> 2, akc = (tid & 3) * 8;
    const int brow = tid >> 1, bkc = (tid & 1) * 16;

    f32x4 acc[2][4];
    const f32x4 z = {0.f, 0.f, 0.f, 0.f};
#pragma unroll
    for (int i = 0; i < 2; i++)
#pragma unroll
        for (int j = 0; j < 4; j++) acc[i][j] = z;

    for (int k0 = 0; k0 < K2; k0 += 32) {
        *(uint4*)(As + arow * 40 + akc) =
            *(const uint4*)(cat + (long)(m0 + arow) * K2 + k0 + akc);
        const unsigned short* src = WfcR + (long)(n0 + brow) * K2 + k0 + bkc;
        *(uint4*)(Bs + brow * 40 + bkc)     = *(const uint4*)src;
        *(uint4*)(Bs + brow * 40 + bkc + 8) = *(const uint4*)(src + 8);
        __syncthreads();
        bf16x8 a0 = *(const bf16x8*)(As + (wm * 32 + l16) * 40 + quad * 8);
        bf16x8 a1 = *(const bf16x8*)(As + (wm * 32 + 16 + l16) * 40 + quad * 8);
#pragma unroll
        for (int j = 0; j < 4; j++) {
            bf16x8 bb = *(const bf16x8*)(Bs + (wn * 64 + j * 16 + l16) * 40 + quad * 8);
            acc[0][j] = MFMA16(a0, bb, acc[0][j]);
            acc[1][j] = MFMA16(a1, bb, acc[1][j]);
        }
        __syncthreads();
    }
#pragma unroll
    for (int i = 0; i < 2; i++)
#pragma unroll
        for (int j = 0; j < 4; j++)
#pragma unroll
            for (int r = 0; r < 4; r++) {
                int row = m0 + wm * 32 + i * 16 + quad * 4 + r;
                int col = n0 + wn * 64 + j * 16 + l16;
                out[(long)row * O_ + col] = acc[i][j][r] + bfc[col];
            }
}

// ---------------------------------------------------------------------------
extern "C" void kernel_launch(void* const* d_in, const int* in_sizes, int n_in,
                              void* d_out, int out_size, void* d_ws, size_t ws_size,
                              hipStream_t stream) {
    const float* x   = (const float*)d_in[0];
    const float* enc = (const float*)d_in[1];
    const float* Wih = (const float*)d_in[2];
    const float* Whh = (const float*)d_in[3];
    const float* bih = (const float*)d_in[4];
    const float* bhh = (const float*)d_in[5];
    const float* Wfc = (const float*)d_in[6];
    const float* bfc = (const float*)d_in[7];
    float* out = (float*)d_out;

    char* ws = (char*)d_ws;
    // workspace layout (bytes); total ~68.2 MB
    unsigned short* WIHR = (unsigned short*)(ws + 0);          //  2,097,152
    unsigned short* WHHR = (unsigned short*)(ws + 2097152);    //  8,388,608
    unsigned short* WFCR = (unsigned short*)(ws + 10485760);   //  1,048,576
    float*          BIAS = (float*)         (ws + 11534336);   //     16,384
    unsigned short* XS   = (unsigned short*)(ws + 11550720);   //  4,194,304
    unsigned short* H0   = (unsigned short*)(ws + 15745024);   //    524,288
    unsigned short* H1   = (unsigned short*)(ws + 16269312);   //    524,288
    float*          C    = (float*)         (ws + 16793600);   //  1,048,576
    unsigned short* HALL = (unsigned short*)(ws + 17842176);   // 16,777,216
    unsigned short* CAT  = (unsigned short*)(ws + 34619392);   // 33,554,432

    prep_kernel<<<4096, 256, 0, stream>>>(x, Wih, Whh, bih, bhh, Wfc,
                                          WIHR, WHHR, WFCR, BIAS, XS, H0, H1, C);

    for (int t = 0; t < T_; t++) {
        const unsigned short* hp = (t & 1) ? H1 : H0;
        unsigned short* hn = (t & 1) ? H0 : H1;
        step_kernel<<<dim3(32, 4), 256, 0, stream>>>(XS, WIHR, WHHR, BIAS,
                                                     hp, hn, C, HALL, t);
    }

    attn_kernel<<<B_, 256, 0, stream>>>(enc, HALL, out + (long)B_ * T_ * O_, CAT);
    fc_kernel<<<dim3(2, 128), 256, 0, stream>>>(CAT, WFCR, bfc, out);
}

// Round 2
// 1113.234 us; speedup vs baseline: 1.0384x; 1.0384x over previous
//
#include <hip/hip_runtime.h>
#include <math.h>

// Problem constants
#define B_  256
#define T_  32
#define S_  128
#define I_  256
#define H_  1024
#define O_  256
#define G4  4096   // 4*H
#define K2  2048   // 2*H

typedef __attribute__((ext_vector_type(8))) short bf16x8;
typedef __attribute__((ext_vector_type(4))) float f32x4;

#define MFMA16(a, b, c) __builtin_amdgcn_mfma_f32_16x16x32_bf16(a, b, c, 0, 0, 0)

__device__ __forceinline__ unsigned short f2bf(float f) {
    unsigned int u = __float_as_uint(f);
    u = (u + 0x7FFFu + ((u >> 16) & 1u)) >> 16;
    return (unsigned short)u;
}
__device__ __forceinline__ float sigm(float x) { return 1.0f / (1.0f + __expf(-x)); }

// ---------------------------------------------------------------------------
// prep: bf16-convert + gate-reorder weights, convert x (zero t=0), convert
// enc -> encB bf16, zero h0/h1/c.  Gate reorder: row r -> n = 4*(r%H)+(r/H).
// ---------------------------------------------------------------------------
__global__ void prep_kernel(
    const float* __restrict__ x, const float* __restrict__ enc,
    const float* __restrict__ Wih, const float* __restrict__ Whh,
    const float* __restrict__ bih, const float* __restrict__ bhh,
    const float* __restrict__ Wfc,
    unsigned short* __restrict__ WihR, unsigned short* __restrict__ WhhR,
    unsigned short* __restrict__ WfcR, float* __restrict__ biasR,
    unsigned short* __restrict__ xs, unsigned short* __restrict__ encB,
    unsigned short* __restrict__ h0, unsigned short* __restrict__ h1,
    float* __restrict__ c)
{
    const long NWHH = (long)G4 * H_;      // 4,194,304
    const long NWIH = (long)G4 * I_;      // 1,048,576
    const long NWFC = (long)O_ * K2;      //   524,288
    const long NB   = G4;
    const long NX   = (long)B_ * T_ * I_; // 2,097,152
    const long NE   = (long)B_ * S_ * H_; // 33,554,432
    const long NH   = (long)B_ * H_;      //   262,144
    const long total = NWHH + NWIH + NWFC + NB + NX + NE + 3 * NH;
    for (long i = (long)blockIdx.x * blockDim.x + threadIdx.x; i < total;
         i += (long)gridDim.x * blockDim.x) {
        long j = i;
        if (j < NE) { encB[j] = f2bf(enc[j]); continue; }
        j -= NE;
        if (j < NWHH) {
            int r = (int)(j >> 10), k = (int)(j & 1023);
            int n = ((r & 1023) << 2) | (r >> 10);
            WhhR[(long)n * H_ + k] = f2bf(Whh[j]);
            continue;
        }
        j -= NWHH;
        if (j < NWIH) {
            int r = (int)(j >> 8), k = (int)(j & 255);
            int n = ((r & 1023) << 2) | (r >> 10);
            WihR[(long)n * I_ + k] = f2bf(Wih[j]);
            continue;
        }
        j -= NWIH;
        if (j < NWFC) { WfcR[j] = f2bf(Wfc[j]); continue; }
        j -= NWFC;
        if (j < NB) {
            int r = (int)j;
            int n = ((r & 1023) << 2) | (r >> 10);
            biasR[n] = bih[r] + bhh[r];
            continue;
        }
        j -= NB;
        if (j < NX) {
            int t = (int)((j >> 8) & 31);
            xs[j] = (t == 0) ? (unsigned short)0 : f2bf(x[j]);
            continue;
        }
        j -= NX;
        if (j < NH) { h0[j] = 0; continue; }
        j -= NH;
        if (j < NH) { h1[j] = 0; continue; }
        j -= NH;
        c[j] = 0.0f;
    }
}

// ---------------------------------------------------------------------------
// step: gates = [x_t, h_prev] @ [WihR; WhhR]^T + biasR, fused LSTM cell.
// M=256, N=4096 (4u+gate), K=1280. Tile 64x64, grid(64,4) = 256 blocks.
// NO LDS in the K-loop: A and B fragments loaded direct global->VGPR
// (lane16 -> row, quad -> k-chunk: 16 rows x 64B lines, fully consumed).
// Weights stay L2-resident across the 32 steps. Epilogue: gates -> small
// LDS -> sigmoid/tanh -> c,h update (64 rows x 16 units per block).
// ---------------------------------------------------------------------------
__global__ __launch_bounds__(256) void step_kernel(
    const unsigned short* __restrict__ xs,   // [B][T][I] bf16
    const unsigned short* __restrict__ WihR, // [4H][I]
    const unsigned short* __restrict__ WhhR, // [4H][H]
    const float* __restrict__ biasR,         // [4H]
    const unsigned short* __restrict__ hprev,// [B][H] bf16
    unsigned short* __restrict__ hnext,      // [B][H] bf16
    float* __restrict__ c,                   // [B][H]
    unsigned short* __restrict__ hall,       // [B][T][H] bf16
    int t)
{
    __shared__ float Gs[64 * 68];  // 17408 B, epilogue only

    const int tid = threadIdx.x;
    const int lane = tid & 63, wave = tid >> 6;
    const int wm = wave >> 1, wn = wave & 1;
    const int quad = lane >> 4, l16 = lane & 15;
    const int n0 = blockIdx.x * 64, m0 = blockIdx.y * 64;

    const int ar0 = m0 + wm * 32 + l16, ar1 = ar0 + 16;
    const int br0 = n0 + wn * 32 + l16, br1 = br0 + 16;

    const unsigned short* ax0 = xs + ((long)ar0 * T_ + t) * I_ + quad * 8;
    const unsigned short* ax1 = xs + ((long)ar1 * T_ + t) * I_ + quad * 8;
    const unsigned short* ah0 = hprev + (long)ar0 * H_ + quad * 8;
    const unsigned short* ah1 = hprev + (long)ar1 * H_ + quad * 8;
    const unsigned short* bx0 = WihR + (long)br0 * I_ + quad * 8;
    const unsigned short* bx1 = WihR + (long)br1 * I_ + quad * 8;
    const unsigned short* bh0 = WhhR + (long)br0 * H_ + quad * 8;
    const unsigned short* bh1 = WhhR + (long)br1 * H_ + quad * 8;

    const f32x4 z = {0.f, 0.f, 0.f, 0.f};
    f32x4 acc00 = z, acc01 = z, acc10 = z, acc11 = z;

    // phase 1: x @ Wih^T  (K = 256)
#pragma unroll
    for (int k0 = 0; k0 < I_; k0 += 32) {
        bf16x8 a0 = *(const bf16x8*)(ax0 + k0);
        bf16x8 a1 = *(const bf16x8*)(ax1 + k0);
        bf16x8 b0 = *(const bf16x8*)(bx0 + k0);
        bf16x8 b1 = *(const bf16x8*)(bx1 + k0);
        acc00 = MFMA16(a0, b0, acc00);
        acc01 = MFMA16(a0, b1, acc01);
        acc10 = MFMA16(a1, b0, acc10);
        acc11 = MFMA16(a1, b1, acc11);
    }
    // phase 2: h @ Whh^T  (K = 1024)
#pragma unroll 4
    for (int k0 = 0; k0 < H_; k0 += 32) {
        bf16x8 a0 = *(const bf16x8*)(ah0 + k0);
        bf16x8 a1 = *(const bf16x8*)(ah1 + k0);
        bf16x8 b0 = *(const bf16x8*)(bh0 + k0);
        bf16x8 b1 = *(const bf16x8*)(bh1 + k0);
        acc00 = MFMA16(a0, b0, acc00);
        acc01 = MFMA16(a0, b1, acc01);
        acc10 = MFMA16(a1, b0, acc10);
        acc11 = MFMA16(a1, b1, acc11);
    }

    // gates + bias -> LDS (C layout: row = quad*4+r, col = l16)
    const float bj0 = biasR[n0 + wn * 32 + l16];
    const float bj1 = biasR[n0 + wn * 32 + 16 + l16];
#pragma unroll
    for (int r = 0; r < 4; r++) {
        int row0 = wm * 32 + quad * 4 + r;
        int col0 = wn * 32 + l16;
        Gs[row0 * 68 + col0]            = acc00[r] + bj0;
        Gs[row0 * 68 + col0 + 16]       = acc01[r] + bj1;
        Gs[(row0 + 16) * 68 + col0]      = acc10[r] + bj0;
        Gs[(row0 + 16) * 68 + col0 + 16] = acc11[r] + bj1;
    }
    __syncthreads();

    // fused cell: 64 rows x 16 units
#pragma unroll
    for (int p = tid; p < 1024; p += 256) {
        int row = p >> 4, u = p & 15;
        float gi = Gs[row * 68 + u * 4 + 0];
        float gf = Gs[row * 68 + u * 4 + 1];
        float gg = Gs[row * 68 + u * 4 + 2];
        float go = Gs[row * 68 + u * 4 + 3];
        int b = m0 + row;
        int jg = (n0 >> 2) + u;
        float ii = sigm(gi), ff = sigm(gf), g3 = tanhf(gg), oo = sigm(go);
        float cn = ff * c[(long)b * H_ + jg] + ii * g3;
        float hh = oo * tanhf(cn);
        c[(long)b * H_ + jg] = cn;
        unsigned short hb = f2bf(hh);
        hnext[(long)b * H_ + jg] = hb;
        hall[((long)b * T_ + t) * H_ + jg] = hb;
    }
}

// ---------------------------------------------------------------------------
// scores: per-b S = hall[b](32x1024) @ encB[b]^T (128x1024)^T, fused softmax.
// Direct global->VGPR K-loop (no barrier until softmax). Writes probs fp32
// (d_out) + P bf16 (workspace). grid(B).
// ---------------------------------------------------------------------------
__global__ __launch_bounds__(256) void scores_kernel(
    const unsigned short* __restrict__ hall, // [B][T][H]
    const unsigned short* __restrict__ encB, // [B][S][H]
    float* __restrict__ probs,               // [B][T][S]
    unsigned short* __restrict__ PB)         // [B][T][S] bf16
{
    __shared__ float Sc[32 * 132];

    const int tid = threadIdx.x;
    const int lane = tid & 63, wave = tid >> 6;
    const int quad = lane >> 4, l16 = lane & 15;
    const int b = blockIdx.x;
    const int nw = wave;  // 4 waves x 32 s-cols

    const unsigned short* pa0 = hall + ((long)b * T_ + l16) * H_ + quad * 8;
    const unsigned short* pa1 = hall + ((long)b * T_ + 16 + l16) * H_ + quad * 8;
    const unsigned short* pb0 = encB + ((long)b * S_ + nw * 32 + l16) * H_ + quad * 8;
    const unsigned short* pb1 = pb0 + 16 * H_;

    const f32x4 z = {0.f, 0.f, 0.f, 0.f};
    f32x4 acc00 = z, acc01 = z, acc10 = z, acc11 = z;

#pragma unroll 4
    for (int k0 = 0; k0 < H_; k0 += 32) {
        bf16x8 a0 = *(const bf16x8*)(pa0 + k0);
        bf16x8 a1 = *(const bf16x8*)(pa1 + k0);
        bf16x8 b0 = *(const bf16x8*)(pb0 + k0);
        bf16x8 b1 = *(const bf16x8*)(pb1 + k0);
        acc00 = MFMA16(a0, b0, acc00);
        acc01 = MFMA16(a0, b1, acc01);
        acc10 = MFMA16(a1, b0, acc10);
        acc11 = MFMA16(a1, b1, acc11);
    }
#pragma unroll
    for (int r = 0; r < 4; r++) {
        int row0 = quad * 4 + r;
        int col0 = nw * 32 + l16;
        Sc[row0 * 132 + col0]            = acc00[r];
        Sc[row0 * 132 + col0 + 16]       = acc01[r];
        Sc[(row0 + 16) * 132 + col0]      = acc10[r];
        Sc[(row0 + 16) * 132 + col0 + 16] = acc11[r];
    }
    __syncthreads();
    // softmax: wave handles 8 rows; 128 cols = 2 per lane
    for (int r = 0; r < 8; r++) {
        int row = wave * 8 + r;
        float v0 = Sc[row * 132 + lane];
        float v1 = Sc[row * 132 + 64 + lane];
        float mx = fmaxf(v0, v1);
#pragma unroll
        for (int off = 32; off > 0; off >>= 1) mx = fmaxf(mx, __shfl_xor(mx, off));
        float e0 = __expf(v0 - mx), e1 = __expf(v1 - mx);
        float s = e0 + e1;
#pragma unroll
        for (int off = 32; off > 0; off >>= 1) s += __shfl_xor(s, off);
        float inv = 1.0f / s;
        float p0 = e0 * inv, p1 = e1 * inv;
        long o = ((long)b * T_ + row) * S_;
        probs[o + lane] = p0;
        probs[o + 64 + lane] = p1;
        PB[o + lane] = f2bf(p0);
        PB[o + 64 + lane] = f2bf(p1);
    }
}

// ---------------------------------------------------------------------------
// ctx: C[b] = P[b](32x128) @ encB[b](128x1024) -> CTX bf16. grid(B, 4), each
// block a 256-wide h chunk. encB chunk staged [s][h] in LDS (64 KB); B-frags
// gathered as 8x ds_read_u16 (k-strided). A-frags direct from PB.
// ---------------------------------------------------------------------------
__global__ __launch_bounds__(256) void ctx_kernel(
    const unsigned short* __restrict__ encB, // [B][S][H]
    const unsigned short* __restrict__ PB,   // [B][T][S]
    unsigned short* __restrict__ ctxo)       // [B*T][H] bf16
{
    __shared__ unsigned short Es[S_ * 256];  // 64 KB

    const int tid = threadIdx.x;
    const int lane = tid & 63, wave = tid >> 6;
    const int quad = lane >> 4, l16 = lane & 15;
    const int b = blockIdx.x;
    const int h0 = blockIdx.y * 256;

    // stage encB[b][:, h0:h0+256] -> LDS [s][256]
    for (int i = tid; i < S_ * 32; i += 256) {
        int s = i >> 5, hc = (i & 31) * 8;
        *(uint4*)(Es + s * 256 + hc) =
            *(const uint4*)(encB + ((long)b * S_ + s) * H_ + h0 + hc);
    }
    // A fragments (P rows t, k = s), direct loads
    bf16x8 a[2][4];
#pragma unroll
    for (int i = 0; i < 2; i++)
#pragma unroll
        for (int ks = 0; ks < 4; ks++)
            a[i][ks] = *(const bf16x8*)(PB + ((long)b * T_ + i * 16 + l16) * S_ +
                                        ks * 32 + quad * 8);
    __syncthreads();

    f32x4 acc[2][4];
    const f32x4 z = {0.f, 0.f, 0.f, 0.f};
#pragma unroll
    for (int i = 0; i < 2; i++)
#pragma unroll
        for (int j = 0; j < 4; j++) acc[i][j] = z;

    const int cw = wave * 64;
#pragma unroll
    for (int ks = 0; ks < 4; ks++) {
        const int kb = ks * 32 + quad * 8;
#pragma unroll
        for (int j = 0; j < 4; j++) {
            const int col = cw + j * 16 + l16;
            bf16x8 bb;
#pragma unroll
            for (int e = 0; e < 8; e++) bb[e] = (short)Es[(kb + e) * 256 + col];
            acc[0][j] = MFMA16(a[0][ks], bb, acc[0][j]);
            acc[1][j] = MFMA16(a[1][ks], bb, acc[1][j]);
        }
    }
#pragma unroll
    for (int i = 0; i < 2; i++)
#pragma unroll
        for (int j = 0; j < 4; j++)
#pragma unroll
            for (int r = 0; r < 4; r++) {
                int row = i * 16 + quad * 4 + r;
                int col = h0 + cw + j * 16 + l16;
                ctxo[((long)b * T_ + row) * H_ + col] = f2bf(acc[i][j][r]);
            }
}

// ---------------------------------------------------------------------------
// fc: out = [ctx | h](8192x2048) @ WfcR^T (256x2048) + bfc. A-tile k<1024
// reads CTX, else hall. Tile 64x128, grid(2,128).
// ---------------------------------------------------------------------------
__global__ __launch_bounds__(256) void fc_kernel(
    const unsigned short* __restrict__ ctxo, // [B*T][H]
    const unsigned short* __restrict__ hall, // [B*T][H]
    const unsigned short* __restrict__ WfcR,
    const float* __restrict__ bfc,
    float* __restrict__ out)
{
    __shared__ __align__(16) unsigned short As[64 * 40];
    __shared__ __align__(16) unsigned short Bs[128 * 40];

    const int tid = threadIdx.x;
    const int lane = tid & 63, wave = tid >> 6;
    const int wm = wave >> 1, wn = wave & 1;
    const int quad = lane >> 4, l16 = lane & 15;
    const int n0 = blockIdx.x * 128, m0 = blockIdx.y * 64;

    const int arow = tid >> 2, akc = (tid & 3) * 8;
    const int brow = tid >> 1, bkc = (tid & 1) * 16;

    f32x4 acc[2][4];
    const f32x4 z = {0.f, 0.f, 0.f, 0.f};
#pragma unroll
    for (int i = 0; i < 2; i++)
#pragma unroll
        for (int j = 0; j < 4; j++) acc[i][j] = z;

    for (int k0 = 0; k0 < K2; k0 += 32) {
        const unsigned short* asrc = (k0 < H_)
            ? ctxo + (long)(m0 + arow) * H_ + k0 + akc
            : hall + (long)(m0 + arow) * H_ + (k0 - H_) + akc;
        *(uint4*)(As + arow * 40 + akc) = *(const uint4*)asrc;
        const unsigned short* src = WfcR + (long)(n0 + brow) * K2 + k0 + bkc;
        *(uint4*)(Bs + brow * 40 + bkc)     = *(const uint4*)src;
        *(uint4*)(Bs + brow * 40 + bkc + 8) = *(const uint4*)(src + 8);
        __syncthreads();
        bf16x8 a0 = *(const bf16x8*)(As + (wm * 32 + l16) * 40 + quad * 8);
        bf16x8 a1 = *(const bf16x8*)(As + (wm * 32 + 16 + l16) * 40 + quad * 8);
#pragma unroll
        for (int j = 0; j < 4; j++) {
            bf16x8 bb = *(const bf16x8*)(Bs + (wn * 64 + j * 16 + l16) * 40 + quad * 8);
            acc[0][j] = MFMA16(a0, bb, acc[0][j]);
            acc[1][j] = MFMA16(a1, bb, acc[1][j]);
        }
        __syncthreads();
    }
#pragma unroll
    for (int i = 0; i < 2; i++)
#pragma unroll
        for (int j = 0; j < 4; j++)
#pragma unroll
            for (int r = 0; r < 4; r++) {
                int row = m0 + wm * 32 + i * 16 + quad * 4 + r;
                int col = n0 + wn * 64 + j * 16 + l16;
                out[(long)row * O_ + col] = acc[i][j][r] + bfc[col];
            }
}

// ---------------------------------------------------------------------------
extern "C" void kernel_launch(void* const* d_in, const int* in_sizes, int n_in,
                              void* d_out, int out_size, void* d_ws, size_t ws_size,
                              hipStream_t stream) {
    const float* x   = (const float*)d_in[0];
    const float* enc = (const float*)d_in[1];
    const float* Wih = (const float*)d_in[2];
    const float* Whh = (const float*)d_in[3];
    const float* bih = (const float*)d_in[4];
    const float* bhh = (const float*)d_in[5];
    const float* Wfc = (const float*)d_in[6];
    const float* bfc = (const float*)d_in[7];
    float* out = (float*)d_out;

    char* ws = (char*)d_ws;
    // workspace layout (bytes); total ~120.6 MB
    unsigned short* WIHR = (unsigned short*)(ws + 0);           //  2,097,152
    unsigned short* WHHR = (unsigned short*)(ws + 2097152);     //  8,388,608
    unsigned short* WFCR = (unsigned short*)(ws + 10485760);    //  1,048,576
    float*          BIAS = (float*)         (ws + 11534336);    //     16,384
    unsigned short* XS   = (unsigned short*)(ws + 11550720);    //  4,194,304
    unsigned short* H0   = (unsigned short*)(ws + 15745024);    //    524,288
    unsigned short* H1   = (unsigned short*)(ws + 16269312);    //    524,288
    float*          C    = (float*)         (ws + 16793600);    //  1,048,576
    unsigned short* HALL = (unsigned short*)(ws + 17842176);    // 16,777,216
    unsigned short* ENCB = (unsigned short*)(ws + 34619392);    // 67,108,864
    unsigned short* PB   = (unsigned short*)(ws + 101728256);   //  2,097,152
    unsigned short* CTX  = (unsigned short*)(ws + 103825408);   // 16,777,216

    prep_kernel<<<8192, 256, 0, stream>>>(x, enc, Wih, Whh, bih, bhh, Wfc,
                                          WIHR, WHHR, WFCR, BIAS, XS, ENCB,
                                          H0, H1, C);

    for (int t = 0; t < T_; t++) {
        const unsigned short* hp = (t & 1) ? H1 : H0;
        unsigned short* hn = (t & 1) ? H0 : H1;
        step_kernel<<<dim3(64, 4), 256, 0, stream>>>(XS, WIHR, WHHR, BIAS,
                                                     hp, hn, C, HALL, t);
    }

    scores_kernel<<<B_, 256, 0, stream>>>(HALL, ENCB,
                                          out + (long)B_ * T_ * O_, PB);
    ctx_kernel<<<dim3(B_, 4), 256, 0, stream>>>(ENCB, PB, CTX);
    fc_kernel<<<dim3(2, 128), 256, 0, stream>>>(CTX, HALL, WFCR, bfc, out);
}